// Round 4
// baseline (565.896 us; speedup 1.0000x reference)
//
#include <hip/hip_runtime.h>
#include <hip/hip_bf16.h>

typedef unsigned short u16;
typedef unsigned int u32;

#define N_TOK 4096
#define DIM   1024
#define HID   4096
#define N_EXP 8
#define CAP   1280

typedef short short8 __attribute__((ext_vector_type(8)));
typedef float f32x4 __attribute__((ext_vector_type(4)));

__device__ __forceinline__ u16 bf16rne(float f) {
    u32 u = __float_as_uint(f);
    u32 r = u + 0x7FFFu + ((u >> 16) & 1u);
    return (u16)(r >> 16);
}
__device__ __forceinline__ float bf2f(u16 h) {
    return __uint_as_float(((u32)h) << 16);
}
__device__ __forceinline__ void atomAddF32(float* p, float v) {
    // fp32 atomic add at device scope (resolves at memory-side cache).
    asm volatile("global_atomic_add_f32 %0, %1, off" :: "v"(p), "v"(v) : "memory");
}

#define GLDS(gp, lp) __builtin_amdgcn_global_load_lds( \
    (const __attribute__((address_space(1))) void*)(gp), \
    (__attribute__((address_space(3))) void*)(lp), 16, 0, 0)

#define SBAR  asm volatile("s_barrier" ::: "memory")
#define LGKM0 asm volatile("s_waitcnt lgkmcnt(0)" ::: "memory")
#define VMW8  asm volatile("s_waitcnt vmcnt(8)" ::: "memory")
#define VMW5  asm volatile("s_waitcnt vmcnt(5)" ::: "memory")
#define VMW0  asm volatile("s_waitcnt vmcnt(0)" ::: "memory")

// ---------------- Router: one wave per token ----------------
__global__ void router_kernel(const float* __restrict__ x,
                              const float* __restrict__ gw,
                              int* __restrict__ r_eidx,
                              float* __restrict__ r_w) {
    const int wave = threadIdx.x >> 6, lane = threadIdx.x & 63;
    const int t = blockIdx.x * 4 + wave;
    const float* xr = x + (size_t)t * DIM;
    float acc[8];
#pragma unroll
    for (int e = 0; e < 8; e++) acc[e] = 0.f;
#pragma unroll 4
    for (int i = 0; i < DIM / 64; i++) {
        int d = i * 64 + lane;
        float xv = xr[d];
        const float4* g = (const float4*)(gw + (size_t)d * 8);
        float4 g0 = g[0], g1 = g[1];
        acc[0] += xv * g0.x; acc[1] += xv * g0.y;
        acc[2] += xv * g0.z; acc[3] += xv * g0.w;
        acc[4] += xv * g1.x; acc[5] += xv * g1.y;
        acc[6] += xv * g1.z; acc[7] += xv * g1.w;
    }
#pragma unroll
    for (int e = 0; e < 8; e++) {
#pragma unroll
        for (int off = 32; off > 0; off >>= 1)
            acc[e] += __shfl_xor(acc[e], off, 64);
    }
    if (lane == 0) {
        int e0 = 0; float l0 = acc[0];
#pragma unroll
        for (int e = 1; e < 8; e++) if (acc[e] > l0) { l0 = acc[e]; e0 = e; }
        int e1 = -1; float l1 = -1e30f;
#pragma unroll
        for (int e = 0; e < 8; e++) if (e != e0 && acc[e] > l1) { l1 = acc[e]; e1 = e; }
        float z = __expf(l1 - l0);          // <= 1
        float inv = 1.f / (1.f + z);
        r_eidx[t] = e0; r_eidx[N_TOK + t] = e1;
        r_w[t] = inv;   r_w[N_TOK + t] = z * inv;
    }
}

// ---------------- Capacity assignment: single block, deterministic scan ------
// Emits: token_for_slot[e*CAP+rank] = tok, wslot[e*CAP+rank] = router weight.
__global__ void assign_kernel(const int* __restrict__ r_eidx,
                              const float* __restrict__ r_w,
                              float* __restrict__ wslot,
                              int* __restrict__ token_for_slot,
                              int* __restrict__ used) {
    const int tid = threadIdx.x;                 // 0..1023
    __shared__ int wtot[8][16];
    __shared__ int wbase[8][16];
    for (int i = tid; i < N_EXP * CAP; i += 1024) token_for_slot[i] = -1;

    int le[8], lr[8], cnt[8];
#pragma unroll
    for (int e = 0; e < 8; e++) cnt[e] = 0;
#pragma unroll
    for (int j = 0; j < 8; j++) {
        int e = r_eidx[tid * 8 + j];
        le[j] = e;
        int r = 0;
#pragma unroll
        for (int e2 = 0; e2 < 8; e2++)
            if (e == e2) { r = cnt[e2]; cnt[e2] = r + 1; }
        lr[j] = r;
    }
    const int lane = tid & 63, wv = tid >> 6;    // 16 waves
    int excl[8];
#pragma unroll
    for (int e = 0; e < 8; e++) {
        int v = cnt[e], inc = v;
#pragma unroll
        for (int off = 1; off < 64; off <<= 1) {
            int u = __shfl_up(inc, off, 64);
            if (lane >= off) inc += u;
        }
        excl[e] = inc - v;
        if (lane == 63) wtot[e][wv] = inc;
    }
    __syncthreads();
    if (tid < 8) {
        int s = 0;
        for (int w = 0; w < 16; w++) { wbase[tid][w] = s; s += wtot[tid][w]; }
        used[tid] = s < CAP ? s : CAP;
    }
    __syncthreads();
#pragma unroll
    for (int j = 0; j < 8; j++) {
        int i = tid * 8 + j;
        int e = le[j];
        int b = 0;
#pragma unroll
        for (int e2 = 0; e2 < 8; e2++)
            if (e == e2) b = wbase[e2][wv] + excl[e2];
        int rank = b + lr[j];
        int tok = i & (N_TOK - 1);
        if (rank < CAP) {
            token_for_slot[e * CAP + rank] = tok;
            wslot[e * CAP + rank] = r_w[i];
        }
    }
}

// ---------------- Gather tokens into per-expert batches (bf16) ----------------
__global__ void gather_kernel(const float* __restrict__ x,
                              const int* __restrict__ token_for_slot,
                              u16* __restrict__ exp_batches) {
    const int s = blockIdx.x;
    const int tok = token_for_slot[s];
    const int d = threadIdx.x * 4;
    ushort4 o;
    if (tok >= 0) {
        float4 v = *(const float4*)(x + (size_t)tok * DIM + d);
        o = make_ushort4(bf16rne(v.x), bf16rne(v.y), bf16rne(v.z), bf16rne(v.w));
    } else {
        o = make_ushort4(0, 0, 0, 0);
    }
    *(ushort4*)(exp_batches + (size_t)s * DIM + d) = o;
}

// ---------------- Weight transpose+convert: f32 [R][C] -> bf16 [C][R] --------
__global__ __launch_bounds__(256) void transpose_cvt(
    const float* __restrict__ in, u16* __restrict__ out, int R, int C) {
    __shared__ float t[64][65];
    const int ez = blockIdx.z;
    in  += (size_t)ez * R * C;
    out += (size_t)ez * R * C;
    const int row0 = blockIdx.y * 64, col0 = blockIdx.x * 64;
    const int tid = threadIdx.x;
    {
        const int r = tid >> 2, cq = (tid & 3) * 16;
        const float* p = in + (size_t)(row0 + r) * C + col0 + cq;
        float4 v0 = ((const float4*)p)[0];
        float4 v1 = ((const float4*)p)[1];
        float4 v2 = ((const float4*)p)[2];
        float4 v3 = ((const float4*)p)[3];
        float tmp[16] = {v0.x, v0.y, v0.z, v0.w, v1.x, v1.y, v1.z, v1.w,
                         v2.x, v2.y, v2.z, v2.w, v3.x, v3.y, v3.z, v3.w};
#pragma unroll
        for (int j = 0; j < 16; j++) t[r][cq + j] = tmp[j];
    }
    __syncthreads();
    {
        const int oc = tid >> 2, h4 = (tid & 3) * 16;
        u16 o[16];
#pragma unroll
        for (int i = 0; i < 16; i++) o[i] = bf16rne(t[h4 + i][oc]);
        u16* q = out + (size_t)(col0 + oc) * R + row0 + h4;
        *(uint4*)q = *(const uint4*)&o[0];
        *(uint4*)(q + 8) = *(const uint4*)&o[8];
    }
}

// ---------------- Unified persistent MFMA GEMM, 3-buffer ring, BK=64 ---------
// A:[CAP,K] bf16 rm per expert; Bt:[N,K] bf16 rm (pre-transposed weights).
// 256 blocks (1/CU; expert = bid&7 -> XCD affinity).  Block keeps its A
// row-tile (rgrp, BM rows) and sweeps TPB B col-panels (col0 = (cg+q*NCG)*256)
// -> B panels L2-shared by the RB blocks of the same cg; A restaged from L2.
// Pipeline: 3 LDS buffers (buf g%3), stage distance 2, ONE flat K-stream of
// G = TPB*NTILE iterations crossing segment boundaries; epilogues run inside
// the stream (stores are issued after stage(g+2), so the next waitL's counted
// vmcnt also retires them - in-order retirement makes this safe).  vmcnt(0)
// only at g = G-2.  Race audit: buffer (g+2)%3 was last READ at iter g-1 and
// the pre-stage barrier at iter g proves all waves finished those reads.
// EPI=1: h = gelu(acc+bias) -> bf16 store.  EPI=2: fused combine -
// out[tok] += w * (acc + bias) via fp32 atomics (2 commutative adds -> exact).
// K-accumulation order identical to baseline -> h bit-identical.
template <int BM, int TPB, int NTILE, int EPI>
__global__ __launch_bounds__(512, 2) void moe_gemmT(
    const u16* __restrict__ A, const u16* __restrict__ Bt,
    const float* __restrict__ bias, u16* __restrict__ Cb,
    float* __restrict__ outF, const int* __restrict__ tfs_,
    const float* __restrict__ wsl_, const int* __restrict__ used,
    int N, int K) {
    constexpr int MI   = BM / 32;            // per-wave M frags (5)
    constexpr int ALW  = BM / 32;            // A-loads per A-wave per k-tile
    constexpr int BUFE = (BM + 256) * 64;    // u16 per buffer
    constexpr int RB   = CAP / BM;           // row groups (8)
    constexpr int NCG  = 32 / RB;            // col groups (4)
    constexpr int LNT  = (NTILE == 16) ? 4 : 6;
    constexpr int G    = TPB * NTILE;        // total k-iters (64)
    __shared__ __align__(16) u16 lds[3 * BUFE];   // 159,744 B

    const int bid = blockIdx.x;
    const int e = bid & 7;                   // expert == XCD affinity
    const int local = bid >> 3;              // 0..31
    const int rgrp = local % RB;
    const int cg   = local / RB;
    const int row0 = rgrp * BM;
    if (row0 >= used[e]) return;             // uniform; same rows all segments

    A    += (size_t)e * CAP * K;
    Bt   += (size_t)e * N * K;
    bias += (size_t)e * N;
    if constexpr (EPI == 1) Cb += (size_t)e * CAP * N;

    const int tid = threadIdx.x;
    const int lane = tid & 63, wave = tid >> 6;
    const int mh   = wave >> 2;              // M-half AND staging role (0=A,1=B)
    const int wv4  = wave & 3;
    const int wr   = mh * (BM / 2);
    const int wc64 = wv4 * 64;

    // ---- staging geometry (proven 0-conflict XOR k-chunk scheme) ----
    const int srow = lane >> 3;
    const int swz  = ((lane & 7) ^ srow) * 8;
    const int ro0  = wv4 * (mh ? 8 : ALW) * 8;
    const size_t segB = (size_t)NCG * 256 * K;    // B panel step per segment
    const u16* gp = (mh ? Bt + (size_t)(cg * 256 + ro0 + srow) * K
                        : A  + (size_t)(row0 + ro0 + srow) * K) + swz;
    u16* dwb = lds + (mh ? BM * 64 : 0) + ro0 * 64;

    auto stage = [&](int g, int buf) {
        const u16* sb = gp + (size_t)(g & (NTILE - 1)) * 64;
        if (mh) sb += (size_t)(g >> LNT) * segB;     // A: same addrs (L2 hits)
        u16* db = dwb + (size_t)buf * BUFE;
        if (mh) {
#pragma unroll
            for (int i = 0; i < 8; ++i)
                GLDS(sb + (size_t)(i * 8) * K, db + i * 512);
        } else {
#pragma unroll
            for (int i = 0; i < ALW; ++i)
                GLDS(sb + (size_t)(i * 8) * K, db + i * 512);
        }
    };
    auto waitL = [&]() { if (mh) { VMW8; } else { VMW5; } };

    // ---- fragment-read geometry ----
    const int rrd = lane & 15, qrd = lane >> 4;
    const int k0 = ((qrd ^ (rrd & 7)) << 3);
    const int k1 = (((4 + qrd) ^ (rrd & 7)) << 3);
    const int aoff = (wr + rrd) * 64;
    const int boff = (wc64 + rrd) * 64;
    const int cr = qrd * 4;
    const int cc = rrd;

    f32x4 acc[MI][4];
#pragma unroll
    for (int i = 0; i < MI; i++)
#pragma unroll
        for (int j = 0; j < 4; j++) acc[i][j] = (f32x4){0.f, 0.f, 0.f, 0.f};

    // ---- prologue: stage g0,g1; own loads for g0 done; all waves joined ----
    stage(0, 0);
    stage(1, 1);
    waitL();
    SBAR;

    int bcur = 0, bst = 2, q = 0;
    for (int g = 0; g < G; ++g) {
        const u16* As = lds + bcur * BUFE;
        const u16* Bs = As + BM * 64;

        short8 bf0[4], bf1[4];
#pragma unroll
        for (int j = 0; j < 4; ++j) {
            bf0[j] = *(const short8*)(Bs + boff + j * 1024 + k0);
            bf1[j] = *(const short8*)(Bs + boff + j * 1024 + k1);
        }
#pragma unroll
        for (int i = 0; i < MI; ++i) {
            short8 a0 = *(const short8*)(As + aoff + i * 1024 + k0);
            short8 a1 = *(const short8*)(As + aoff + i * 1024 + k1);
            __builtin_amdgcn_s_setprio(1);
#pragma unroll
            for (int j = 0; j < 4; ++j)
                acc[i][j] = __builtin_amdgcn_mfma_f32_16x16x32_bf16(
                    a0, bf0[j], acc[i][j], 0, 0, 0);
#pragma unroll
            for (int j = 0; j < 4; ++j)
                acc[i][j] = __builtin_amdgcn_mfma_f32_16x16x32_bf16(
                    a1, bf1[j], acc[i][j], 0, 0, 0);
            __builtin_amdgcn_s_setprio(0);
        }

        if (g < G - 1) {
            LGKM0;                               // own ds_reads retired
            __builtin_amdgcn_sched_barrier(0);   // rule-18 fence
            SBAR;                                // all waves' reads retired
            if (g + 2 < G) {
                stage(g + 2, bst);               // refill buffer read at g-1
                waitL();                         // g+1 arrived (g+2 in flight)
                bst = (bst == 2) ? 0 : bst + 1;
            } else {
                VMW0;                            // tail only
            }
            SBAR;                                // buffer g+1 visible to all
        }
        bcur = (bcur == 2) ? 0 : bcur + 1;

        // ---- segment epilogue (registers + global only; no LDS, no sync) ----
        if ((g & (NTILE - 1)) == NTILE - 1) {
            const int col0 = (cg + q * NCG) * 256;
            if constexpr (EPI == 1) {
                float bv[4];
#pragma unroll
                for (int j = 0; j < 4; ++j) bv[j] = bias[col0 + wc64 + j * 16 + cc];
#pragma unroll
                for (int i = 0; i < MI; ++i) {
#pragma unroll
                    for (int r = 0; r < 4; ++r) {
                        const int row = row0 + wr + i * 16 + cr + r;
                        u16* cp = Cb + (size_t)row * N + col0 + wc64 + cc;
#pragma unroll
                        for (int j = 0; j < 4; ++j) {
                            float v = acc[i][j][r] + bv[j];
                            float uu = 0.7978845608f * v * (1.f + 0.044715f * v * v);
                            v = v / (1.f + __expf(-2.f * uu));
                            cp[j * 16] = bf16rne(v);
                        }
                    }
                }
            } else {   // EPI == 2: fused combine, fp32 atomics
                const int* tfs = tfs_ + e * CAP;
                const float* wsl = wsl_ + e * CAP;
                float bv[4];
#pragma unroll
                for (int j = 0; j < 4; ++j) bv[j] = bias[col0 + wc64 + j * 16 + cc];
#pragma unroll
                for (int i = 0; i < MI; ++i) {
#pragma unroll
                    for (int r = 0; r < 4; ++r) {
                        const int row = row0 + wr + i * 16 + cr + r;
                        const int tok = tfs[row];
                        if (tok >= 0) {
                            const float w = wsl[row];
                            float* op = outF + (size_t)tok * DIM + col0 + wc64 + cc;
#pragma unroll
                            for (int j = 0; j < 4; ++j)
                                atomAddF32(op + j * 16, w * (acc[i][j][r] + bv[j]));
                        }
                    }
                }
            }
#pragma unroll
            for (int i = 0; i < MI; i++)
#pragma unroll
                for (int j = 0; j < 4; j++) acc[i][j] = (f32x4){0.f, 0.f, 0.f, 0.f};
            ++q;
        }
    }
}

// ---------------- Launch ----------------
extern "C" void kernel_launch(void* const* d_in, const int* in_sizes, int n_in,
                              void* d_out, int out_size, void* d_ws, size_t ws_size,
                              hipStream_t stream) {
    const float* x         = (const float*)d_in[0];
    const float* gate_w    = (const float*)d_in[1];
    const float* c_fc      = (const float*)d_in[2];
    const float* fc_bias   = (const float*)d_in[3];
    const float* c_proj    = (const float*)d_in[4];
    const float* proj_bias = (const float*)d_in[5];
    float* out = (float*)d_out;
    char* ws = (char*)d_ws;

    // workspace layout (bytes)
    int*   r_eidx         = (int*)(ws + 0);              //  32 KB
    float* r_w            = (float*)(ws + 32768);        //  32 KB
    float* wslot          = (float*)(ws + 65536);        //  40 KB
    int*   token_for_slot = (int*)(ws + 106496);         //  40 KB
    int*   used           = (int*)(ws + 147456);         //  32 B (pad to 163840)
    u16*   exp_batches    = (u16*)(ws + 163840);         //  20.97 MB [10240,1024]
    u16*   h              = (u16*)(ws + 21135360);       //  83.9  MB [10240,4096]
    u16*   Bt             = (u16*)(ws + 105021440);      //  64 MB (Bt1 then Bt2)
    // total: 172,130,304 bytes (~164 MB)

    hipMemsetAsync(out, 0, (size_t)N_TOK * DIM * sizeof(float), stream);
    router_kernel<<<N_TOK / 4, 256, 0, stream>>>(x, gate_w, r_eidx, r_w);
    assign_kernel<<<1, 1024, 0, stream>>>(r_eidx, r_w, wslot, token_for_slot, used);
    gather_kernel<<<N_EXP * CAP, 256, 0, stream>>>(x, token_for_slot, exp_batches);

    // Bt1 = c_fc^T per expert: [D,H] -> [H,D]
    transpose_cvt<<<dim3(HID / 64, DIM / 64, N_EXP), 256, 0, stream>>>(
        c_fc, Bt, DIM, HID);
    // GEMM1: [CAP,1024] x [4096,1024]^T.  BM=160, 4-segment col sweep,
    // NTILE=16 -> one flat 64-iter pipeline per block; 256 blocks (1/CU).
    moe_gemmT<160, 4, 16, 1><<<256, 512, 0, stream>>>(
        exp_batches, Bt, fc_bias, h, nullptr, nullptr, nullptr, used, HID, DIM);

    // Bt2 = c_proj^T per expert: [H,D] -> [D,H]  (aliases Bt1, now dead)
    transpose_cvt<<<dim3(DIM / 64, HID / 64, N_EXP), 256, 0, stream>>>(
        c_proj, Bt, HID, DIM);
    // GEMM2: [CAP,4096] x [1024,4096]^T.  BM=160, 1 segment, NTILE=64;
    // epilogue scatters w*(acc+bias) into out via fp32 atomics (combine fused).
    moe_gemmT<160, 1, 64, 2><<<256, 512, 0, stream>>>(
        h, Bt, proj_bias, nullptr, out, token_for_slot, wslot, used, DIM, HID);
}